// Round 6
// baseline (1326.627 us; speedup 1.0000x reference)
//
#include <hip/hip_runtime.h>

// Problem constants (fixed by the reference file)
constexpr int Bn = 4, Hn = 16, Sn = 2048, Dn = 64;
constexpr float MASK_FILL = -1e9f;
constexpr size_t KV_ELEMS = (size_t)Bn * Hn * Sn * Dn;   // 8,388,608

typedef __bf16 bf16x8 __attribute__((ext_vector_type(8)));
typedef __bf16 bf16x4 __attribute__((ext_vector_type(4)));
typedef float  f32x4  __attribute__((ext_vector_type(4)));
typedef int    i32x4  __attribute__((ext_vector_type(4)));

// LDS strides in elements (__bf16).
#define KSTRIDE 72    // K and Q/S-scratch tiles: [128 rows][64+pad]
#define VSTRIDE 136   // V-transposed tile: [64 d-rows][128 k + pad]

// Raw barrier: waits only LDS ops, NOT vmcnt — attn stores stay in flight.
#define BARRIER_LGKM() asm volatile("s_waitcnt lgkmcnt(0)\n\ts_barrier" ::: "memory")

// Pre-pass: convert K,V to bf16 in workspace. Traffic model: the attn kernel
// is HBM-bound at ~3.2GB/launch, of which ~2GB is K/V re-fetch (16 q-tile
// blocks/bh x 2MB fp32, zero cache reuse because the 1.07GB attn stream
// cycles L3 4x and 4 concurrent bh x 2MB > 4MB L2). bf16 halves K/V bytes
// and fits the per-XCD working set into L2.
__global__ __launch_bounds__(256) void convert_kv(
    const float* __restrict__ kg, const float* __restrict__ vg,
    __bf16* __restrict__ kb, __bf16* __restrict__ vb)
{
  const size_t n4 = KV_ELEMS / 4;
  const size_t stride = (size_t)gridDim.x * 256;
  for (size_t i = (size_t)blockIdx.x * 256 + threadIdx.x; i < n4; i += stride) {
    f32x4 kv = __builtin_nontemporal_load((const f32x4*)(kg + i * 4));
    bf16x4 pk;
    pk.x = (__bf16)kv.x; pk.y = (__bf16)kv.y;
    pk.z = (__bf16)kv.z; pk.w = (__bf16)kv.w;
    *(bf16x4*)(kb + i * 4) = pk;            // plain store: keep cached (read 16x soon)
    f32x4 vv = __builtin_nontemporal_load((const f32x4*)(vg + i * 4));
    bf16x4 pv;
    pv.x = (__bf16)vv.x; pv.y = (__bf16)vv.y;
    pv.z = (__bf16)vv.z; pv.w = (__bf16)vv.w;
    *(bf16x4*)(vb + i * 4) = pv;
  }
}

// Fused attention (no softmax): per block computes a 128-row Q stripe of one
// (b,h). Both MFMAs are operand-swapped (mfma(K,Q), mfma(V,S)) so each lane
// holds 4 consecutive attn columns -> all global stores are f32x4.
// kt phase stagger (round 5, -80us): spreads concurrent stores across all 16
// column ranges = all DRAM channels. attn stores are NONTEMPORAL so the write
// stream doesn't evict bf16 K/V from L2/L3 (nt was time-neutral vs plain in
// round-4 A/B, so this costs nothing if the cache theory is wrong).
template <bool PRE>
__global__ __launch_bounds__(256, 2) void attn_fused(
    const float* __restrict__ qg, const float* __restrict__ kg,
    const float* __restrict__ vg, const int* __restrict__ maskg,
    float* __restrict__ outg, float* __restrict__ attng,
    const __bf16* __restrict__ kbg, const __bf16* __restrict__ vbg)
{
  __shared__ __align__(16) __bf16 lds_k [128 * KSTRIDE];
  __shared__ __align__(16) __bf16 lds_vt[ 64 * VSTRIDE];
  __shared__ __align__(16) __bf16 lds_qs[128 * KSTRIDE];  // Q tile, then per-wave S scratch
  __shared__ __align__(16) int    lds_m [Sn];             // full mask row for this b

  // Bijective XCD swizzle (1024 wg, 8 XCDs): all 16 qt blocks of a bh land on
  // the same XCD -> K/V shareable in its 4MB L2 (bf16: 4 bh x 1MB fits).
  const int fid  = blockIdx.y * gridDim.x + blockIdx.x;
  const int nf   = ((fid & 7) << 7) | (fid >> 3);
  const int qt   = nf & 15;           // 0..15 query tile
  const int bh   = nf >> 4;           // 0..63 (b*16+h)
  const int b    = bh >> 4;
  const int tid  = threadIdx.x;
  const int wave = tid >> 6;
  const int lane = tid & 63;
  const int quad = lane >> 4;
  const int l16  = lane & 15;

  const int kt0  = nf & 15;           // per-block K-tile phase offset

  const size_t hbase = (size_t)bh * Sn * Dn;
  const float* qp = qg + hbase + (size_t)qt * 128 * Dn;
  float* attnp = attng + (size_t)bh * Sn * Sn + (size_t)qt * 128 * (size_t)Sn;

  const int r0 = tid >> 4;          // 0..15
  const int c  = (tid & 15) << 2;   // 0..60

  // ---- stage full mask row (once per block) ----
  {
    const int* mp = maskg + b * Sn;
    *(i32x4*)&lds_m[tid * 8]     = *(const i32x4*)(mp + tid * 8);
    *(i32x4*)&lds_m[tid * 8 + 4] = *(const i32x4*)(mp + tid * 8 + 4);
  }

  // ---- stage Q tile (pre-scaled by 1/temperature = 0.125, exact pow2) ----
#pragma unroll
  for (int i = 0; i < 8; ++i) {
    const int r = r0 + (i << 4);
    f32x4 val = __builtin_nontemporal_load((const f32x4*)(qp + r * Dn + c));
    bf16x4 pk;
    pk.x = (__bf16)(val.x * 0.125f);
    pk.y = (__bf16)(val.y * 0.125f);
    pk.z = (__bf16)(val.z * 0.125f);
    pk.w = (__bf16)(val.w * 0.125f);
    *(bf16x4*)&lds_qs[r * KSTRIDE + c] = pk;
  }

  // ---- prefetch K/V tile kt0 into registers (issue early, write late) ----
  // K rows: r0 + 16i. V rows: r0*8 + i (8 CONSECUTIVE k so the LDS transpose
  // write is a single b128 per d-col). PRE path loads bf16 directly (half BW).
  f32x4  kpre [8], vpre [8];
  bf16x4 kpreb[8], vpreb[8];
  const float*  kbase  = kg  + hbase;
  const float*  vbase  = vg  + hbase;
  const __bf16* kbbase = PRE ? (kbg + hbase) : nullptr;
  const __bf16* vbbase = PRE ? (vbg + hbase) : nullptr;
  {
    const size_t toff = (size_t)(kt0 * 128) * Dn;
#pragma unroll
    for (int i = 0; i < 8; ++i) {
      if constexpr (PRE) {
        kpreb[i] = *(const bf16x4*)(kbbase + toff + (r0 + (i << 4)) * Dn + c);
        vpreb[i] = *(const bf16x4*)(vbbase + toff + (r0 * 8 + i) * Dn + c);
      } else {
        kpre[i] = *(const f32x4*)(kbase + toff + (r0 + (i << 4)) * Dn + c);
        vpre[i] = *(const f32x4*)(vbase + toff + (r0 * 8 + i) * Dn + c);
      }
    }
  }

  BARRIER_LGKM();

  // ---- hoist per-wave Q fragments (frag layout: [n=lane&15][k=quad*8+j]) ----
  bf16x8 qa[2][2];
#pragma unroll
  for (int qs = 0; qs < 2; ++qs)
#pragma unroll
    for (int ks = 0; ks < 2; ++ks)
      qa[qs][ks] = *(const bf16x8*)&lds_qs[(wave * 32 + qs * 16 + l16) * KSTRIDE + ks * 32 + quad * 8];

  // Per-wave private S scratch aliases this wave's own 32 rows of the Q tile.
  __bf16* sbuf = &lds_qs[wave * 32 * KSTRIDE];

  f32x4 oacc[2][4];
#pragma unroll
  for (int qs = 0; qs < 2; ++qs)
#pragma unroll
    for (int ds = 0; ds < 4; ++ds)
      oacc[qs][ds] = (f32x4){0.f, 0.f, 0.f, 0.f};

  for (int it = 0; it < 16; ++it) {
    const int kt = (it + kt0) & 15;   // phase-staggered tile index
    BARRIER_LGKM();   // all waves done reading previous K/V LDS tiles

    // ---- write prefetched K (row-major) and V (reg-transposed) as bf16 ----
#pragma unroll
    for (int i = 0; i < 8; ++i) {
      const int r = r0 + (i << 4);
      if constexpr (PRE) {
        *(bf16x4*)&lds_k[r * KSTRIDE + c] = kpreb[i];
      } else {
        f32x4 kv = kpre[i];
        bf16x4 pk;
        pk.x = (__bf16)kv.x; pk.y = (__bf16)kv.y;
        pk.z = (__bf16)kv.z; pk.w = (__bf16)kv.w;
        *(bf16x4*)&lds_k[r * KSTRIDE + c] = pk;
      }
    }
#pragma unroll
    for (int j = 0; j < 4; ++j) {       // d-col = c + j
      bf16x8 t;
#pragma unroll
      for (int i = 0; i < 8; ++i)       // k-row = r0*8 + i (consecutive)
        t[i] = PRE ? vpreb[i][j] : (__bf16)vpre[i][j];
      *(bf16x8*)&lds_vt[(c + j) * VSTRIDE + r0 * 8] = t;
    }

    BARRIER_LGKM();   // publish K/V tile

    // ---- issue next tile's loads BEFORE this tile's stores (FIFO vmcnt:
    //      loads older than stores -> LDS-write wait never drains stores) ----
    if (it < 15) {
      const int ktn = (it + 1 + kt0) & 15;
      const size_t toff = (size_t)(ktn * 128) * Dn;
#pragma unroll
      for (int i = 0; i < 8; ++i) {
        if constexpr (PRE) {
          kpreb[i] = *(const bf16x4*)(kbbase + toff + (r0 + (i << 4)) * Dn + c);
          vpreb[i] = *(const bf16x4*)(vbbase + toff + (r0 * 8 + i) * Dn + c);
        } else {
          kpre[i] = *(const f32x4*)(kbase + toff + (r0 + (i << 4)) * Dn + c);
          vpre[i] = *(const f32x4*)(vbase + toff + (r0 * 8 + i) * Dn + c);
        }
      }
    }

    // ---- S = K @ Q^T (swapped) fused with mask-fill + nt f32x4 attn stores ----
    f32x4 sacc[2][8];
#pragma unroll
    for (int ns = 0; ns < 8; ++ns) {
      bf16x8 ka0 = *(const bf16x8*)&lds_k[(ns * 16 + l16) * KSTRIDE +      quad * 8];
      bf16x8 ka1 = *(const bf16x8*)&lds_k[(ns * 16 + l16) * KSTRIDE + 32 + quad * 8];
      const i32x4 m4 = *(const i32x4*)&lds_m[kt * 128 + ns * 16 + quad * 4];
#pragma unroll
      for (int qs = 0; qs < 2; ++qs) {
        f32x4 acc = (f32x4){0.f, 0.f, 0.f, 0.f};
        acc = __builtin_amdgcn_mfma_f32_16x16x32_bf16(ka0, qa[qs][0], acc, 0, 0, 0);
        acc = __builtin_amdgcn_mfma_f32_16x16x32_bf16(ka1, qa[qs][1], acc, 0, 0, 0);
        acc.x = m4.x ? acc.x : MASK_FILL;
        acc.y = m4.y ? acc.y : MASK_FILL;
        acc.z = m4.z ? acc.z : MASK_FILL;
        acc.w = m4.w ? acc.w : MASK_FILL;
        sacc[qs][ns] = acc;
        const int row = wave * 32 + qs * 16 + l16;
        __builtin_nontemporal_store(acc,
            (f32x4*)(attnp + (size_t)row * Sn + kt * 128 + ns * 16 + quad * 4));
      }
    }

    // ---- O += S @ V, two 64-col halves; S through per-wave LDS scratch,
    //      V via bf16x8 reads from the transposed tile ----
#pragma unroll
    for (int half = 0; half < 2; ++half) {
#pragma unroll
      for (int ns4 = 0; ns4 < 4; ++ns4) {
        const int ns = half * 4 + ns4;
#pragma unroll
        for (int qs = 0; qs < 2; ++qs) {
          f32x4 sv = sacc[qs][ns];
          bf16x4 sb;
          sb.x = (__bf16)sv.x; sb.y = (__bf16)sv.y;
          sb.z = (__bf16)sv.z; sb.w = (__bf16)sv.w;
          *(bf16x4*)&sbuf[(qs * 16 + l16) * KSTRIDE + ns4 * 16 + quad * 4] = sb;
        }
      }
      asm volatile("" ::: "memory");
#pragma unroll
      for (int ks = 0; ks < 2; ++ks) {
        bf16x8 sb0 = *(const bf16x8*)&sbuf[(     l16) * KSTRIDE + ks * 32 + quad * 8];
        bf16x8 sb1 = *(const bf16x8*)&sbuf[(16 + l16) * KSTRIDE + ks * 32 + quad * 8];
#pragma unroll
        for (int ds = 0; ds < 4; ++ds) {
          bf16x8 va = *(const bf16x8*)&lds_vt[(ds * 16 + l16) * VSTRIDE + half * 64 + ks * 32 + quad * 8];
          // swapped: D[m = d-offset][n = q-row] -> epilogue stores are f32x4
          oacc[0][ds] = __builtin_amdgcn_mfma_f32_16x16x32_bf16(va, sb0, oacc[0][ds], 0, 0, 0);
          oacc[1][ds] = __builtin_amdgcn_mfma_f32_16x16x32_bf16(va, sb1, oacc[1][ds], 0, 0, 0);
        }
      }
      asm volatile("" ::: "memory");  // keep next half's sbuf writes after these reads
    }
  }

  // ---- epilogue: vectorized O stores (lane holds 4 consecutive d) ----
  float* op = outg + hbase + (size_t)qt * 128 * Dn;
#pragma unroll
  for (int qs = 0; qs < 2; ++qs)
#pragma unroll
    for (int ds = 0; ds < 4; ++ds) {
      const int row = wave * 32 + qs * 16 + l16;
      __builtin_nontemporal_store(oacc[qs][ds],
          (f32x4*)(op + (size_t)row * Dn + ds * 16 + quad * 4));
    }
}

extern "C" void kernel_launch(void* const* d_in, const int* in_sizes, int n_in,
                              void* d_out, int out_size, void* d_ws, size_t ws_size,
                              hipStream_t stream) {
  const float* q    = (const float*)d_in[0];
  const float* k    = (const float*)d_in[1];
  const float* v    = (const float*)d_in[2];
  const int*   mask = (const int*)d_in[3];
  float* out  = (float*)d_out;
  float* attn = out + (size_t)Bn * Hn * Sn * Dn;   // outputs concatenated: (output, attn)

  dim3 grid(Sn / 128, Bn * Hn);
  const size_t need = KV_ELEMS * 2 * sizeof(__bf16);   // kb + vb = 33.6 MB
  if (d_ws != nullptr && ws_size >= need) {
    __bf16* kb = (__bf16*)d_ws;
    __bf16* vb = kb + KV_ELEMS;
    convert_kv<<<2048, 256, 0, stream>>>(k, v, kb, vb);
    attn_fused<true><<<grid, 256, 0, stream>>>(q, k, v, mask, out, attn, kb, vb);
  } else {
    attn_fused<false><<<grid, 256, 0, stream>>>(q, k, v, mask, out, attn, nullptr, nullptr);
  }
}

// Round 7
// 1183.822 us; speedup vs baseline: 1.1206x; 1.1206x over previous
//
#include <hip/hip_runtime.h>

// Problem constants (fixed by the reference file)
constexpr int Bn = 4, Hn = 16, Sn = 2048, Dn = 64;
constexpr float MASK_FILL = -1e9f;
constexpr size_t KV_ELEMS = (size_t)Bn * Hn * Sn * Dn;   // 8,388,608

typedef __bf16 bf16x8 __attribute__((ext_vector_type(8)));
typedef __bf16 bf16x4 __attribute__((ext_vector_type(4)));
typedef float  f32x4  __attribute__((ext_vector_type(4)));
typedef int    i32x4  __attribute__((ext_vector_type(4)));

// LDS strides in elements (__bf16).
#define KSTRIDE 72    // K and Q/S-scratch tiles: [128 rows][64+pad]
#define VSTRIDE 136   // V-transposed tile: [64 d-rows][128 k + pad]

// Raw barrier: waits only LDS ops, NOT vmcnt — attn stores stay in flight.
#define BARRIER_LGKM() asm volatile("s_waitcnt lgkmcnt(0)\n\ts_barrier" ::: "memory")

// Pre-pass: convert K,V to bf16 in workspace (halves K/V fetch bytes in the
// attn kernel; K/V bf16 total 33.6MB is trivially L3-resident).
__global__ __launch_bounds__(256) void convert_kv(
    const float* __restrict__ kg, const float* __restrict__ vg,
    __bf16* __restrict__ kb, __bf16* __restrict__ vb)
{
  const size_t n4 = KV_ELEMS / 4;
  const size_t stride = (size_t)gridDim.x * 256;
  for (size_t i = (size_t)blockIdx.x * 256 + threadIdx.x; i < n4; i += stride) {
    f32x4 kv = __builtin_nontemporal_load((const f32x4*)(kg + i * 4));
    bf16x4 pk;
    pk.x = (__bf16)kv.x; pk.y = (__bf16)kv.y;
    pk.z = (__bf16)kv.z; pk.w = (__bf16)kv.w;
    *(bf16x4*)(kb + i * 4) = pk;            // plain store: read 16x soon
    f32x4 vv = __builtin_nontemporal_load((const f32x4*)(vg + i * 4));
    bf16x4 pv;
    pv.x = (__bf16)vv.x; pv.y = (__bf16)vv.y;
    pv.z = (__bf16)vv.z; pv.w = (__bf16)vv.w;
    *(bf16x4*)(vb + i * 4) = pv;
  }
}

// Fused attention (no softmax): per block computes a 128-row Q stripe of one
// (b,h). Both MFMAs are operand-swapped (mfma(K,Q), mfma(V,S)) so each lane
// holds 4 consecutive attn columns -> all global stores are f32x4.
// kt phase stagger (round 5, -80us) + PLAIN cacheable attn stores: R6's A/B
// showed nontemporal stores cost ~90us WITH the stagger (neutral without) —
// plain stores let the per-XCD L2 aggregate the staggered write bursts.
template <bool PRE>
__global__ __launch_bounds__(256, 2) void attn_fused(
    const float* __restrict__ qg, const float* __restrict__ kg,
    const float* __restrict__ vg, const int* __restrict__ maskg,
    float* __restrict__ outg, float* __restrict__ attng,
    const __bf16* __restrict__ kbg, const __bf16* __restrict__ vbg)
{
  __shared__ __align__(16) __bf16 lds_k [128 * KSTRIDE];
  __shared__ __align__(16) __bf16 lds_vt[ 64 * VSTRIDE];
  __shared__ __align__(16) __bf16 lds_qs[128 * KSTRIDE];  // Q tile, then per-wave S scratch
  __shared__ __align__(16) int    lds_m [Sn];             // full mask row for this b

  // Bijective XCD swizzle (1024 wg, 8 XCDs): all 16 qt blocks of a bh land on
  // the same XCD -> K/V shareable in its 4MB L2 (bf16: 4 bh x 1MB fits).
  const int fid  = blockIdx.y * gridDim.x + blockIdx.x;
  const int nf   = ((fid & 7) << 7) | (fid >> 3);
  const int qt   = nf & 15;           // 0..15 query tile
  const int bh   = nf >> 4;           // 0..63 (b*16+h)
  const int b    = bh >> 4;
  const int tid  = threadIdx.x;
  const int wave = tid >> 6;
  const int lane = tid & 63;
  const int quad = lane >> 4;
  const int l16  = lane & 15;

  const int kt0  = nf & 15;           // per-block K-tile phase offset

  const size_t hbase = (size_t)bh * Sn * Dn;
  const float* qp = qg + hbase + (size_t)qt * 128 * Dn;
  float* attnp = attng + (size_t)bh * Sn * Sn + (size_t)qt * 128 * (size_t)Sn;

  const int r0 = tid >> 4;          // 0..15
  const int c  = (tid & 15) << 2;   // 0..60

  // ---- stage full mask row (once per block) ----
  {
    const int* mp = maskg + b * Sn;
    *(i32x4*)&lds_m[tid * 8]     = *(const i32x4*)(mp + tid * 8);
    *(i32x4*)&lds_m[tid * 8 + 4] = *(const i32x4*)(mp + tid * 8 + 4);
  }

  // ---- stage Q tile (pre-scaled by 1/temperature = 0.125, exact pow2) ----
#pragma unroll
  for (int i = 0; i < 8; ++i) {
    const int r = r0 + (i << 4);
    f32x4 val = __builtin_nontemporal_load((const f32x4*)(qp + r * Dn + c));
    bf16x4 pk;
    pk.x = (__bf16)(val.x * 0.125f);
    pk.y = (__bf16)(val.y * 0.125f);
    pk.z = (__bf16)(val.z * 0.125f);
    pk.w = (__bf16)(val.w * 0.125f);
    *(bf16x4*)&lds_qs[r * KSTRIDE + c] = pk;
  }

  // ---- prefetch K/V tile kt0 into registers (issue early, write late) ----
  // K rows: r0 + 16i. V rows: r0*8 + i (8 CONSECUTIVE k so the LDS transpose
  // write is a single b128 per d-col). PRE path loads bf16 directly (half BW).
  f32x4  kpre [8], vpre [8];
  bf16x4 kpreb[8], vpreb[8];
  const float*  kbase  = kg  + hbase;
  const float*  vbase  = vg  + hbase;
  const __bf16* kbbase = PRE ? (kbg + hbase) : nullptr;
  const __bf16* vbbase = PRE ? (vbg + hbase) : nullptr;
  {
    const size_t toff = (size_t)(kt0 * 128) * Dn;
#pragma unroll
    for (int i = 0; i < 8; ++i) {
      if constexpr (PRE) {
        kpreb[i] = *(const bf16x4*)(kbbase + toff + (r0 + (i << 4)) * Dn + c);
        vpreb[i] = *(const bf16x4*)(vbbase + toff + (r0 * 8 + i) * Dn + c);
      } else {
        kpre[i] = *(const f32x4*)(kbase + toff + (r0 + (i << 4)) * Dn + c);
        vpre[i] = *(const f32x4*)(vbase + toff + (r0 * 8 + i) * Dn + c);
      }
    }
  }

  BARRIER_LGKM();

  // ---- hoist per-wave Q fragments (frag layout: [n=lane&15][k=quad*8+j]) ----
  bf16x8 qa[2][2];
#pragma unroll
  for (int qs = 0; qs < 2; ++qs)
#pragma unroll
    for (int ks = 0; ks < 2; ++ks)
      qa[qs][ks] = *(const bf16x8*)&lds_qs[(wave * 32 + qs * 16 + l16) * KSTRIDE + ks * 32 + quad * 8];

  // Per-wave private S scratch aliases this wave's own 32 rows of the Q tile.
  __bf16* sbuf = &lds_qs[wave * 32 * KSTRIDE];

  f32x4 oacc[2][4];
#pragma unroll
  for (int qs = 0; qs < 2; ++qs)
#pragma unroll
    for (int ds = 0; ds < 4; ++ds)
      oacc[qs][ds] = (f32x4){0.f, 0.f, 0.f, 0.f};

  for (int it = 0; it < 16; ++it) {
    const int kt = (it + kt0) & 15;   // phase-staggered tile index
    BARRIER_LGKM();   // all waves done reading previous K/V LDS tiles

    // ---- write prefetched K (row-major) and V (reg-transposed) as bf16 ----
#pragma unroll
    for (int i = 0; i < 8; ++i) {
      const int r = r0 + (i << 4);
      if constexpr (PRE) {
        *(bf16x4*)&lds_k[r * KSTRIDE + c] = kpreb[i];
      } else {
        f32x4 kv = kpre[i];
        bf16x4 pk;
        pk.x = (__bf16)kv.x; pk.y = (__bf16)kv.y;
        pk.z = (__bf16)kv.z; pk.w = (__bf16)kv.w;
        *(bf16x4*)&lds_k[r * KSTRIDE + c] = pk;
      }
    }
#pragma unroll
    for (int j = 0; j < 4; ++j) {       // d-col = c + j
      bf16x8 t;
#pragma unroll
      for (int i = 0; i < 8; ++i)       // k-row = r0*8 + i (consecutive)
        t[i] = PRE ? vpreb[i][j] : (__bf16)vpre[i][j];
      *(bf16x8*)&lds_vt[(c + j) * VSTRIDE + r0 * 8] = t;
    }

    BARRIER_LGKM();   // publish K/V tile

    // ---- issue next tile's loads BEFORE this tile's stores (FIFO vmcnt:
    //      loads older than stores -> LDS-write wait never drains stores) ----
    if (it < 15) {
      const int ktn = (it + 1 + kt0) & 15;
      const size_t toff = (size_t)(ktn * 128) * Dn;
#pragma unroll
      for (int i = 0; i < 8; ++i) {
        if constexpr (PRE) {
          kpreb[i] = *(const bf16x4*)(kbbase + toff + (r0 + (i << 4)) * Dn + c);
          vpreb[i] = *(const bf16x4*)(vbbase + toff + (r0 * 8 + i) * Dn + c);
        } else {
          kpre[i] = *(const f32x4*)(kbase + toff + (r0 + (i << 4)) * Dn + c);
          vpre[i] = *(const f32x4*)(vbase + toff + (r0 * 8 + i) * Dn + c);
        }
      }
    }

    // ---- S = K @ Q^T (swapped) fused with mask-fill + plain f32x4 stores.
    //      The wave writes both 64B halves of each 128B sector close together
    //      -> L2 merges to full-line writebacks. ----
    f32x4 sacc[2][8];
#pragma unroll
    for (int ns = 0; ns < 8; ++ns) {
      bf16x8 ka0 = *(const bf16x8*)&lds_k[(ns * 16 + l16) * KSTRIDE +      quad * 8];
      bf16x8 ka1 = *(const bf16x8*)&lds_k[(ns * 16 + l16) * KSTRIDE + 32 + quad * 8];
      const i32x4 m4 = *(const i32x4*)&lds_m[kt * 128 + ns * 16 + quad * 4];
#pragma unroll
      for (int qs = 0; qs < 2; ++qs) {
        f32x4 acc = (f32x4){0.f, 0.f, 0.f, 0.f};
        acc = __builtin_amdgcn_mfma_f32_16x16x32_bf16(ka0, qa[qs][0], acc, 0, 0, 0);
        acc = __builtin_amdgcn_mfma_f32_16x16x32_bf16(ka1, qa[qs][1], acc, 0, 0, 0);
        acc.x = m4.x ? acc.x : MASK_FILL;
        acc.y = m4.y ? acc.y : MASK_FILL;
        acc.z = m4.z ? acc.z : MASK_FILL;
        acc.w = m4.w ? acc.w : MASK_FILL;
        sacc[qs][ns] = acc;
        const int row = wave * 32 + qs * 16 + l16;
        *(f32x4*)(attnp + (size_t)row * Sn + kt * 128 + ns * 16 + quad * 4) = acc;
      }
    }

    // ---- O += S @ V, two 64-col halves; S through per-wave LDS scratch,
    //      V via bf16x8 reads from the transposed tile ----
#pragma unroll
    for (int half = 0; half < 2; ++half) {
#pragma unroll
      for (int ns4 = 0; ns4 < 4; ++ns4) {
        const int ns = half * 4 + ns4;
#pragma unroll
        for (int qs = 0; qs < 2; ++qs) {
          f32x4 sv = sacc[qs][ns];
          bf16x4 sb;
          sb.x = (__bf16)sv.x; sb.y = (__bf16)sv.y;
          sb.z = (__bf16)sv.z; sb.w = (__bf16)sv.w;
          *(bf16x4*)&sbuf[(qs * 16 + l16) * KSTRIDE + ns4 * 16 + quad * 4] = sb;
        }
      }
      asm volatile("" ::: "memory");
#pragma unroll
      for (int ks = 0; ks < 2; ++ks) {
        bf16x8 sb0 = *(const bf16x8*)&sbuf[(     l16) * KSTRIDE + ks * 32 + quad * 8];
        bf16x8 sb1 = *(const bf16x8*)&sbuf[(16 + l16) * KSTRIDE + ks * 32 + quad * 8];
#pragma unroll
        for (int ds = 0; ds < 4; ++ds) {
          bf16x8 va = *(const bf16x8*)&lds_vt[(ds * 16 + l16) * VSTRIDE + half * 64 + ks * 32 + quad * 8];
          // swapped: D[m = d-offset][n = q-row] -> epilogue stores are f32x4
          oacc[0][ds] = __builtin_amdgcn_mfma_f32_16x16x32_bf16(va, sb0, oacc[0][ds], 0, 0, 0);
          oacc[1][ds] = __builtin_amdgcn_mfma_f32_16x16x32_bf16(va, sb1, oacc[1][ds], 0, 0, 0);
        }
      }
      asm volatile("" ::: "memory");  // keep next half's sbuf writes after these reads
    }
  }

  // ---- epilogue: vectorized O stores (lane holds 4 consecutive d) ----
  float* op = outg + hbase + (size_t)qt * 128 * Dn;
#pragma unroll
  for (int qs = 0; qs < 2; ++qs)
#pragma unroll
    for (int ds = 0; ds < 4; ++ds) {
      const int row = wave * 32 + qs * 16 + l16;
      __builtin_nontemporal_store(oacc[qs][ds],
          (f32x4*)(op + (size_t)row * Dn + ds * 16 + quad * 4));
    }
}

extern "C" void kernel_launch(void* const* d_in, const int* in_sizes, int n_in,
                              void* d_out, int out_size, void* d_ws, size_t ws_size,
                              hipStream_t stream) {
  const float* q    = (const float*)d_in[0];
  const float* k    = (const float*)d_in[1];
  const float* v    = (const float*)d_in[2];
  const int*   mask = (const int*)d_in[3];
  float* out  = (float*)d_out;
  float* attn = out + (size_t)Bn * Hn * Sn * Dn;   // outputs concatenated: (output, attn)

  dim3 grid(Sn / 128, Bn * Hn);
  const size_t need = KV_ELEMS * 2 * sizeof(__bf16);   // kb + vb = 33.6 MB
  if (d_ws != nullptr && ws_size >= need) {
    __bf16* kb = (__bf16*)d_ws;
    __bf16* vb = kb + KV_ELEMS;
    convert_kv<<<2048, 256, 0, stream>>>(k, v, kb, vb);
    attn_fused<true><<<grid, 256, 0, stream>>>(q, k, v, mask, out, attn, kb, vb);
  } else {
    attn_fused<false><<<grid, 256, 0, stream>>>(q, k, v, mask, out, attn, nullptr, nullptr);
  }
}